// Round 1
// baseline (225.036 us; speedup 1.0000x reference)
//
#include <hip/hip_runtime.h>

#define SQ 4096
#define NB 2
#define NH 4
#define DH 32
#define DM 128

typedef float f32x16 __attribute__((ext_vector_type(16)));
typedef float f32x4  __attribute__((ext_vector_type(4)));
typedef __bf16 bf16x8 __attribute__((ext_vector_type(8)));
typedef unsigned int uint4v __attribute__((ext_vector_type(4)));
typedef unsigned short u16;

union B8 { uint4v u; bf16x8 b; };

__device__ inline u16 f2bf(float x) {
  unsigned u = __builtin_bit_cast(unsigned, x);
  unsigned r = (u + 0x7FFF + ((u >> 16) & 1)) >> 16;
  return (u16)r;
}

__device__ inline unsigned cvt_pk_bf16(float a, float b) {
  unsigned r;
  asm("v_cvt_pk_bf16_f32 %0, %1, %2" : "=v"(r) : "v"(a), "v"(b));
  return r;
}

__device__ inline void swap32(unsigned &a, unsigned &b) {
  asm("v_permlane32_swap_b32 %0, %1" : "+v"(a), "+v"(b));
}

// ---------------- K0a: xsum[b][d] = sum_p x[b,p,d] ----------------
__global__ __launch_bounds__(256) void kxsum(const float* __restrict__ x,
                                             float* __restrict__ xsum) {
  __shared__ float red[256];
  const int t = threadIdx.x;
  const int b = blockIdx.y;
  const int d0 = blockIdx.x * 16;
  const int dd = t & 15, ps = t >> 4;
  float a = 0.f;
  const float* xp = x + (size_t)b * SQ * DM + d0 + dd;
  for (int p = ps; p < SQ; p += 16) a += xp[(size_t)p * DM];
  red[t] = a;
  __syncthreads();
  if (t < 16) {
    float s = 0.f;
#pragma unroll
    for (int j = 0; j < 16; ++j) s += red[j * 16 + t];
    xsum[b * DM + d0 + t] = s;
  }
}

// ---------------- K0b: c[b][d] = 0.5 * W_O @ (W_V @ xsum) ----------------
__global__ __launch_bounds__(128) void kcvec(const float* __restrict__ xsum,
                                             const float* __restrict__ Wv,
                                             const float* __restrict__ Wo,
                                             float* __restrict__ cvec) {
  __shared__ float xs[DM], vs[DM];
  const int t = threadIdx.x;
  const int b = blockIdx.x;
  xs[t] = xsum[b * DM + t];
  __syncthreads();
  float a = 0.f;
  for (int d = 0; d < DM; ++d) a += Wv[t * DM + d] * xs[d];
  vs[t] = a;
  __syncthreads();
  float c = 0.f;
  for (int f = 0; f < DM; ++f) c += Wo[t * DM + f] * vs[f];
  cvec[b * DM + t] = 0.5f * c;
}

// ---------------- K1: projections q,k,v ----------------
// qb/kb: bf16 [b,h,p,32] (q pre-scaled by log2e/sqrt(32))
// vt: bf16 tiled [b,h,tile=p/32][dh][p%32]  (= V^T in 32x32 tiles)
__global__ __launch_bounds__(256) void kproj(const float* __restrict__ x,
                                             const float* __restrict__ Wk,
                                             const float* __restrict__ Wq,
                                             const float* __restrict__ Wv,
                                             u16* __restrict__ qb,
                                             u16* __restrict__ kb,
                                             u16* __restrict__ vt) {
  __shared__ float xT[DM][68];   // [d][pos]
  __shared__ float wT[DM][132];  // [d][col]
  const int t = threadIdx.x;
  const int m = blockIdx.y;  // 0:K 1:Q 2:V
  const float* W = (m == 0) ? Wk : (m == 1 ? Wq : Wv);
  const int P0 = blockIdx.x * 64;
  const float* xblk = x + (size_t)P0 * DM;
  for (int idx = t; idx < 64 * DM; idx += 256) xT[idx & 127][idx >> 7] = xblk[idx];
  for (int idx = t; idx < DM * DM; idx += 256) wT[idx & 127][idx >> 7] = W[idx];
  __syncthreads();
  const int c0 = (t & 31) * 4;
  const int p0 = (t >> 5) * 8;
  float acc[8][4];
#pragma unroll
  for (int p = 0; p < 8; ++p)
#pragma unroll
    for (int c = 0; c < 4; ++c) acc[p][c] = 0.f;
  for (int d = 0; d < DM; ++d) {
    f32x4 xa = *(const f32x4*)&xT[d][p0];
    f32x4 xb = *(const f32x4*)&xT[d][p0 + 4];
    f32x4 wv = *(const f32x4*)&wT[d][c0];
#pragma unroll
    for (int c = 0; c < 4; ++c) {
#pragma unroll
      for (int p = 0; p < 4; ++p) acc[p][c] += xa[p] * wv[c];
#pragma unroll
      for (int p = 0; p < 4; ++p) acc[4 + p][c] += xb[p] * wv[c];
    }
  }
  const float QS = 1.4426950408889634f / 5.656854249492380f;
  const int b = P0 >> 12;
  const int pl0 = P0 & (SQ - 1);
#pragma unroll
  for (int p = 0; p < 8; ++p) {
    int pl = pl0 + p0 + p;
#pragma unroll
    for (int c = 0; c < 4; ++c) {
      int col = c0 + c;
      int hh = col >> 5, dh = col & 31;
      float v = acc[p][c];
      size_t bh = (size_t)(b * NH + hh);
      if (m == 0) {
        kb[(bh * SQ + pl) * DH + dh] = f2bf(v);
      } else if (m == 1) {
        qb[(bh * SQ + pl) * DH + dh] = f2bf(v * QS);
      } else {
        vt[((bh * (SQ / 32) + (pl >> 5)) * DH + dh) * 32 + (pl & 31)] = f2bf(v);
      }
    }
  }
}

// ---------------- K2: fused attention (online softmax), writes yT = 0.5*softmax@V, [b][f][p] fp32
__global__ __launch_bounds__(256) void kattn(const u16* __restrict__ qb,
                                             const u16* __restrict__ kb,
                                             const u16* __restrict__ vt,
                                             float* __restrict__ yT) {
  __shared__ float sm_[2][64], ss_[2][64], sa_[2][16][64];
  const int t = threadIdx.x;
  const int lane = t & 63;
  const int wid = t >> 6;
  const int qs = wid >> 1, kh = wid & 1;
  const int l31 = lane & 31, hi = lane >> 5;
  const int bh = blockIdx.y;  // b*4+h
  const int qglob = blockIdx.x * 64 + qs * 32 + l31;

  const u16* qrow = qb + ((size_t)bh * SQ + qglob) * DH;
  B8 qf0, qf1;
  qf0.u = *(const uint4v*)(qrow + 8 * hi);
  qf1.u = *(const uint4v*)(qrow + 16 + 8 * hi);

  const int NT = (SQ / 2) / 32;  // 64 tiles of 32 keys
  const u16* kT = kb + ((size_t)bh * SQ + kh * (SQ / 2)) * DH;
  const u16* vT = vt + ((size_t)bh * (SQ / 32) + kh * (SQ / 64)) * (DH * 32);
  const int koff = l31 * 32 + 8 * hi;

  B8 k0, k1, v0, v1, k0n, k1n, v0n, v1n;
  k0.u = *(const uint4v*)(kT + koff);
  k1.u = *(const uint4v*)(kT + koff + 16);
  v0.u = *(const uint4v*)(vT + koff);
  v1.u = *(const uint4v*)(vT + koff + 16);

  float m = -1e30f, s = 0.f;
  f32x16 acc;
#pragma unroll
  for (int r = 0; r < 16; ++r) acc[r] = 0.f;

  for (int ti = 0; ti < NT; ++ti) {
    if (ti + 1 < NT) {
      const u16* kn = kT + (ti + 1) * 1024 + koff;
      const u16* vn = vT + (ti + 1) * 1024 + koff;
      k0n.u = *(const uint4v*)(kn);
      k1n.u = *(const uint4v*)(kn + 16);
      v0n.u = *(const uint4v*)(vn);
      v1n.u = *(const uint4v*)(vn + 16);
    }
    // S^T tile: D[key=crow(r,hi)][q=l31]
    f32x16 sc;
#pragma unroll
    for (int r = 0; r < 16; ++r) sc[r] = 0.f;
    sc = __builtin_amdgcn_mfma_f32_32x32x16_bf16(k0.b, qf0.b, sc, 0, 0, 0);
    sc = __builtin_amdgcn_mfma_f32_32x32x16_bf16(k1.b, qf1.b, sc, 0, 0, 0);

    float pm = sc[0];
#pragma unroll
    for (int r = 1; r < 16; ++r) pm = fmaxf(pm, sc[r]);
    pm = fmaxf(pm, __shfl_xor(pm, 32, 64));
    float mnew = fmaxf(m, pm);
    if (__any(mnew > m)) {
      float scale = exp2f(m - mnew);
      s *= scale;
#pragma unroll
      for (int r = 0; r < 16; ++r) acc[r] *= scale;
      m = mnew;
    }
    float p[16];
    float ls = 0.f;
#pragma unroll
    for (int r = 0; r < 16; ++r) {
      p[r] = exp2f(sc[r] - m);
      ls += p[r];
    }
    ls += __shfl_xor(ls, 32, 64);
    s += ls;

    // pack P -> bf16 B-operand fragments via cvt_pk + permlane32_swap
    unsigned w0 = cvt_pk_bf16(p[0], p[1]);
    unsigned w1 = cvt_pk_bf16(p[2], p[3]);
    unsigned w2 = cvt_pk_bf16(p[4], p[5]);
    unsigned w3 = cvt_pk_bf16(p[6], p[7]);
    unsigned w4 = cvt_pk_bf16(p[8], p[9]);
    unsigned w5 = cvt_pk_bf16(p[10], p[11]);
    unsigned w6 = cvt_pk_bf16(p[12], p[13]);
    unsigned w7 = cvt_pk_bf16(p[14], p[15]);
    swap32(w0, w2);
    swap32(w1, w3);
    swap32(w4, w6);
    swap32(w5, w7);
    B8 bp0, bp1;
    bp0.u[0] = w0; bp0.u[1] = w1; bp0.u[2] = w2; bp0.u[3] = w3;
    bp1.u[0] = w4; bp1.u[1] = w5; bp1.u[2] = w6; bp1.u[3] = w7;

    // O^T += V^T * P^T
    acc = __builtin_amdgcn_mfma_f32_32x32x16_bf16(v0.b, bp0.b, acc, 0, 0, 0);
    acc = __builtin_amdgcn_mfma_f32_32x32x16_bf16(v1.b, bp1.b, acc, 0, 0, 0);

    k0 = k0n; k1 = k1n; v0 = v0n; v1 = v1n;
  }

  // merge the two key-halves (waves kh=0,1 with same qs)
  if (kh == 1) {
    sm_[qs][lane] = m;
    ss_[qs][lane] = s;
#pragma unroll
    for (int r = 0; r < 16; ++r) sa_[qs][r][lane] = acc[r];
  }
  __syncthreads();
  if (kh == 0) {
    float m1 = sm_[qs][lane], s1 = ss_[qs][lane];
    float mM = fmaxf(m, m1);
    float e0 = exp2f(m - mM), e1 = exp2f(m1 - mM);
    float inv = 0.5f / (s * e0 + s1 * e1);
#pragma unroll
    for (int r = 0; r < 16; ++r) {
      int row = (r & 3) + 8 * (r >> 2) + 4 * hi;  // h' index
      float o = (acc[r] * e0 + sa_[qs][r][lane] * e1) * inv;
      yT[(size_t)(bh * 32 + row) * SQ + qglob] = o;
    }
  }
}

// ---------------- K3: out[b,p,d] = sum_f Wo[d,f]*y[b,p,f] + c[b,d] ----------------
__global__ __launch_bounds__(256) void kout(const float* __restrict__ yT,
                                            const float* __restrict__ Wo,
                                            const float* __restrict__ cvec,
                                            float* __restrict__ out) {
  __shared__ float yS[DM][32];    // [f][p]
  __shared__ float wT3[DM][132];  // [f][d]
  const int t = threadIdx.x;
  const int b = blockIdx.y;
  const int P0 = blockIdx.x * 32;
  for (int idx = t; idx < DM * 32; idx += 256) {
    int f = idx >> 5, p = idx & 31;
    yS[f][p] = yT[((size_t)b * DM + f) * SQ + P0 + p];
  }
  for (int idx = t; idx < DM * DM; idx += 256) wT3[idx & 127][idx >> 7] = Wo[idx];
  __syncthreads();
  const int d4 = (t & 31) * 4;
  const int p4 = (t >> 5) * 4;
  f32x4 acc4[4];
#pragma unroll
  for (int pp = 0; pp < 4; ++pp) acc4[pp] = (f32x4){0.f, 0.f, 0.f, 0.f};
  for (int f = 0; f < DM; ++f) {
    f32x4 yv = *(const f32x4*)&yS[f][p4];
    f32x4 wv = *(const f32x4*)&wT3[f][d4];
#pragma unroll
    for (int pp = 0; pp < 4; ++pp) acc4[pp] += wv * yv[pp];
  }
  f32x4 cv = *(const f32x4*)&cvec[b * DM + d4];
#pragma unroll
  for (int pp = 0; pp < 4; ++pp) {
    f32x4 o = acc4[pp] + cv;
    *(f32x4*)&out[((size_t)b * SQ + P0 + p4 + pp) * DM + d4] = o;
  }
}

extern "C" void kernel_launch(void* const* d_in, const int* in_sizes, int n_in,
                              void* d_out, int out_size, void* d_ws, size_t ws_size,
                              hipStream_t stream) {
  const float* x  = (const float*)d_in[0];
  const float* Wk = (const float*)d_in[1];
  const float* Wq = (const float*)d_in[2];
  const float* Wv = (const float*)d_in[3];
  const float* Wo = (const float*)d_in[4];
  float* out = (float*)d_out;
  char* ws = (char*)d_ws;
  u16* qb    = (u16*)(ws);
  u16* kb    = (u16*)(ws + (size_t)(2 << 20));
  u16* vt    = (u16*)(ws + (size_t)(4 << 20));
  float* yT  = (float*)(ws + (size_t)(6 << 20));
  float* xsum = (float*)(ws + (size_t)(10 << 20));
  float* cvec = (float*)(ws + (size_t)(10 << 20) + 1024);

  kproj<<<dim3(128, 3), dim3(256), 0, stream>>>(x, Wk, Wq, Wv, qb, kb, vt);
  kxsum<<<dim3(8, 2), dim3(256), 0, stream>>>(x, xsum);
  kcvec<<<dim3(2), dim3(128), 0, stream>>>(xsum, Wv, Wo, cvec);
  kattn<<<dim3(64, 8), dim3(256), 0, stream>>>(qb, kb, vt, yT);
  kout<<<dim3(128, 2), dim3(256), 0, stream>>>(yT, Wo, cvec, out);
}

// Round 3
// 160.067 us; speedup vs baseline: 1.4059x; 1.4059x over previous
//
#include <hip/hip_runtime.h>

#define SQ 4096
#define NB 2
#define NH 4
#define DH 32
#define DM 128

typedef float f32x16 __attribute__((ext_vector_type(16)));
typedef float f32x4  __attribute__((ext_vector_type(4)));
typedef __bf16 bf16x8 __attribute__((ext_vector_type(8)));
typedef unsigned int uint4v __attribute__((ext_vector_type(4)));
typedef unsigned short u16;

union B8 { uint4v u; bf16x8 b; };

__device__ inline u16 f2bf(float x) {
  unsigned u = __builtin_bit_cast(unsigned, x);
  unsigned r = (u + 0x7FFF + ((u >> 16) & 1)) >> 16;
  return (u16)r;
}

__device__ inline float bf2f(u16 v) {
  return __builtin_bit_cast(float, (unsigned)v << 16);
}

__device__ inline unsigned cvt_pk_bf16(float a, float b) {
  unsigned r;
  asm("v_cvt_pk_bf16_f32 %0, %1, %2" : "=v"(r) : "v"(a), "v"(b));
  return r;
}

__device__ inline void swap32(unsigned &a, unsigned &b) {
  asm("v_permlane32_swap_b32 %0, %1" : "+v"(a), "+v"(b));
}

#if __has_builtin(__builtin_amdgcn_exp2f)
#define EX2 __builtin_amdgcn_exp2f
#else
#define EX2 exp2f
#endif

__device__ inline float xhalf_max(float x) {
  unsigned ua = __builtin_bit_cast(unsigned, x), ub = ua;
  asm("v_permlane32_swap_b32 %0, %1" : "+v"(ua), "+v"(ub));
  return fmaxf(__builtin_bit_cast(float, ua), __builtin_bit_cast(float, ub));
}

__device__ inline float xhalf_add(float x) {
  unsigned ua = __builtin_bit_cast(unsigned, x), ub = ua;
  asm("v_permlane32_swap_b32 %0, %1" : "+v"(ua), "+v"(ub));
  return __builtin_bit_cast(float, ua) + __builtin_bit_cast(float, ub);
}

__device__ inline float tmax16(const f32x16& v) {
  float a0 = fmaxf(v[0], v[1]), a1 = fmaxf(v[2], v[3]);
  float a2 = fmaxf(v[4], v[5]), a3 = fmaxf(v[6], v[7]);
  float a4 = fmaxf(v[8], v[9]), a5 = fmaxf(v[10], v[11]);
  float a6 = fmaxf(v[12], v[13]), a7 = fmaxf(v[14], v[15]);
  float b0 = fmaxf(a0, a1), b1 = fmaxf(a2, a3);
  float b2 = fmaxf(a4, a5), b3 = fmaxf(a6, a7);
  return fmaxf(fmaxf(b0, b1), fmaxf(b2, b3));
}

// load 8 consecutive fp32, convert to bf16x8 fragment
__device__ inline bf16x8 ld_cvt8(const float* p) {
  f32x4 a = *(const f32x4*)p;
  f32x4 b = *(const f32x4*)(p + 4);
  B8 r;
  r.u[0] = cvt_pk_bf16(a[0], a[1]);
  r.u[1] = cvt_pk_bf16(a[2], a[3]);
  r.u[2] = cvt_pk_bf16(b[0], b[1]);
  r.u[3] = cvt_pk_bf16(b[2], b[3]);
  return r.b;
}

// ---------------- K1: prep — xsum (32 blocks) + woT transpose (1 block)
__global__ __launch_bounds__(256) void kprep(const float* __restrict__ x,
                                             const float* __restrict__ Wo,
                                             float* __restrict__ woT,
                                             float* __restrict__ xsum) {
  const int bid = blockIdx.x, t = threadIdx.x;
  if (bid < 32) {
    const int b = bid >> 4;       // 16 blocks per batch
    const int rblk = bid & 15;    // 256 rows each
    const int d = t & 127, rh = t >> 7;
    const float* xp = x + ((size_t)b * SQ + rblk * 256) * DM + d;
    float a = 0.f;
    for (int r = rh; r < 256; r += 2) a += xp[(size_t)r * DM];
    __shared__ float red[2][DM];
    red[rh][d] = a;
    __syncthreads();
    if (t < DM) atomicAdd(&xsum[b * DM + t], red[0][t] + red[1][t]);
  } else {
    for (int i = t; i < DM * DM; i += 256) woT[(i & 127) * DM + (i >> 7)] = Wo[i];
  }
}

// ---------------- K2: MFMA projections, on-the-fly fp32->bf16 (+ fused cvec at by==12)
// qb/kb: bf16 [bh][p][dh]; vt: bf16 [bh][ptile][dh][p%32]
__global__ __launch_bounds__(256) void kprojc(const float* __restrict__ x,
                                              const float* __restrict__ Wk,
                                              const float* __restrict__ Wq,
                                              const float* __restrict__ Wv,
                                              const float* __restrict__ Wo,
                                              const float* __restrict__ xsum,
                                              u16* __restrict__ qb,
                                              u16* __restrict__ kb,
                                              u16* __restrict__ vt,
                                              float* __restrict__ cvec) {
  const int by = blockIdx.y;
  const int t = threadIdx.x;
  if (by == 12) {
    // cvec: c[b][d] = 0.5 * Wo @ (Wv @ xsum)
    if (blockIdx.x >= NB) return;
    const int b = blockIdx.x;
    __shared__ float xs[DM], vs[DM];
    if (t < DM) xs[t] = xsum[b * DM + t];
    __syncthreads();
    const int c = t >> 1, half = t & 1;
    float a = 0.f;
    const float* wr = Wv + c * DM + half * 64;
    const float* xh = xs + half * 64;
    for (int i = 0; i < 64; ++i) a += wr[i] * xh[i];
    a += __shfl_xor(a, 1, 64);
    if (half == 0) vs[c] = a;
    __syncthreads();
    float a2 = 0.f;
    const float* wr2 = Wo + c * DM + half * 64;
    const float* vh = vs + half * 64;
    for (int i = 0; i < 64; ++i) a2 += wr2[i] * vh[i];
    a2 += __shfl_xor(a2, 1, 64);
    if (half == 0) cvec[b * DM + c] = 0.5f * a2;
    return;
  }
  const int lane = t & 63, wid = t >> 6;
  const int l31 = lane & 31, hi = lane >> 5;
  const int mat = by >> 2, h = by & 3;   // 0:K 1:Q 2:V
  const int p0 = (blockIdx.x * 4 + wid) * 32;
  const float* xrow = x + (size_t)(p0 + l31) * DM + 8 * hi;
  const float* W = (mat == 0) ? Wk : (mat == 1 ? Wq : Wv);
  const float* wrow = W + (h * 32 + l31) * DM + 8 * hi;
  f32x16 acc;
#pragma unroll
  for (int r = 0; r < 16; ++r) acc[r] = 0.f;
#pragma unroll
  for (int ks = 0; ks < 8; ++ks) {
    bf16x8 af = ld_cvt8(xrow + ks * 16);
    bf16x8 wf = ld_cvt8(wrow + ks * 16);
    acc = __builtin_amdgcn_mfma_f32_32x32x16_bf16(af, wf, acc, 0, 0, 0);
  }
  const float QS = 1.4426950408889634f / 5.656854249492380f;
  const int b = p0 >> 12, pl = p0 & (SQ - 1);
  const size_t bh = (size_t)b * NH + h;
  if (mat == 0) {
    u16* dst = kb + (bh * SQ + pl) * DH + l31;
#pragma unroll
    for (int r = 0; r < 16; ++r) {
      int row = (r & 3) + 8 * (r >> 2) + 4 * hi;
      dst[(size_t)row * DH] = f2bf(acc[r]);
    }
  } else if (mat == 1) {
    u16* dst = qb + (bh * SQ + pl) * DH + l31;
#pragma unroll
    for (int r = 0; r < 16; ++r) {
      int row = (r & 3) + 8 * (r >> 2) + 4 * hi;
      dst[(size_t)row * DH] = f2bf(acc[r] * QS);
    }
  } else {
    u16* dst = vt + ((bh * (SQ / 32) + (pl >> 5)) * DH + l31) * 32;
#pragma unroll
    for (int r = 0; r < 16; ++r) {
      int row = (r & 3) + 8 * (r >> 2) + 4 * hi;
      dst[row] = f2bf(acc[r]);
    }
  }
}

// ---------------- K3: fused attention, 64 q per wave, keys 4-way split per block
#define SOFTMAX_PV(SC, M, S, ACC, V0, V1) {                                    \
  float p_[16];                                                                \
  _Pragma("unroll") for (int r = 0; r < 16; ++r) p_[r] = EX2(SC[r] - M);       \
  float ls = ((p_[0]+p_[1])+(p_[2]+p_[3]))+((p_[4]+p_[5])+(p_[6]+p_[7]));      \
  ls += ((p_[8]+p_[9])+(p_[10]+p_[11]))+((p_[12]+p_[13])+(p_[14]+p_[15]));     \
  S += xhalf_add(ls);                                                          \
  unsigned w0 = cvt_pk_bf16(p_[0], p_[1]),  w1 = cvt_pk_bf16(p_[2], p_[3]);    \
  unsigned w2 = cvt_pk_bf16(p_[4], p_[5]),  w3 = cvt_pk_bf16(p_[6], p_[7]);    \
  unsigned w4 = cvt_pk_bf16(p_[8], p_[9]),  w5 = cvt_pk_bf16(p_[10], p_[11]);  \
  unsigned w6 = cvt_pk_bf16(p_[12], p_[13]), w7 = cvt_pk_bf16(p_[14], p_[15]); \
  swap32(w0, w2); swap32(w1, w3); swap32(w4, w6); swap32(w5, w7);              \
  B8 bp0_, bp1_;                                                               \
  bp0_.u[0] = w0; bp0_.u[1] = w1; bp0_.u[2] = w2; bp0_.u[3] = w3;              \
  bp1_.u[0] = w4; bp1_.u[1] = w5; bp1_.u[2] = w6; bp1_.u[3] = w7;              \
  ACC = __builtin_amdgcn_mfma_f32_32x32x16_bf16(V0.b, bp0_.b, ACC, 0, 0, 0);   \
  ACC = __builtin_amdgcn_mfma_f32_32x32x16_bf16(V1.b, bp1_.b, ACC, 0, 0, 0);   \
}

#define TILE(K0, K1, V0, V1, NOFF) {                                             \
  f32x16 sc0 = __builtin_amdgcn_mfma_f32_32x32x16_bf16(K0.b, qf00.b, zacc, 0,0,0); \
  sc0 = __builtin_amdgcn_mfma_f32_32x32x16_bf16(K1.b, qf01.b, sc0, 0, 0, 0);     \
  f32x16 sc1 = __builtin_amdgcn_mfma_f32_32x32x16_bf16(K0.b, qf10.b, zacc, 0,0,0); \
  sc1 = __builtin_amdgcn_mfma_f32_32x32x16_bf16(K1.b, qf11.b, sc1, 0, 0, 0);     \
  K0.u = *(const uint4v*)(kT + (NOFF));                                          \
  K1.u = *(const uint4v*)(kT + (NOFF) + 16);                                     \
  float pm0 = xhalf_max(tmax16(sc0));                                            \
  float pm1 = xhalf_max(tmax16(sc1));                                            \
  if (__any((pm0 > m0 + 8.f) | (pm1 > m1 + 8.f))) {                              \
    float n0 = fmaxf(m0, pm0), n1 = fmaxf(m1, pm1);                              \
    float r0 = EX2(m0 - n0), r1 = EX2(m1 - n1);                                  \
    s0 *= r0; s1 *= r1;                                                          \
    _Pragma("unroll") for (int r = 0; r < 16; ++r) { acc0[r] *= r0; acc1[r] *= r1; } \
    m0 = n0; m1 = n1;                                                            \
  }                                                                              \
  SOFTMAX_PV(sc0, m0, s0, acc0, V0, V1)                                          \
  SOFTMAX_PV(sc1, m1, s1, acc1, V0, V1)                                          \
  V0.u = *(const uint4v*)(vT + (NOFF));                                          \
  V1.u = *(const uint4v*)(vT + (NOFF) + 16);                                     \
}

__global__ __launch_bounds__(256) void kattn(const u16* __restrict__ qb,
                                             const u16* __restrict__ kb,
                                             const u16* __restrict__ vt,
                                             u16* __restrict__ yT) {
  __shared__ float sm_[3][2][64], ss_[3][2][64], sa_[3][2][16][64];
  const int t = threadIdx.x, lane = t & 63, wid = t >> 6;
  const int l31 = lane & 31, hi = lane >> 5;
  const int bh = blockIdx.y;
  const int qbase = blockIdx.x * 64;

  const u16* qrow0 = qb + ((size_t)bh * SQ + qbase + l31) * DH + 8 * hi;
  const u16* qrow1 = qrow0 + 32 * DH;
  B8 qf00, qf01, qf10, qf11;
  qf00.u = *(const uint4v*)(qrow0);
  qf01.u = *(const uint4v*)(qrow0 + 16);
  qf10.u = *(const uint4v*)(qrow1);
  qf11.u = *(const uint4v*)(qrow1 + 16);

  const int kh = wid;  // key quarter: 1024 keys per wave
  const u16* kT = kb + ((size_t)bh * SQ + kh * 1024) * DH + l31 * 32 + 8 * hi;
  const u16* vT = vt + ((size_t)bh * (SQ / 32) + kh * 32) * (DH * 32) + l31 * 32 + 8 * hi;

  f32x16 zacc, acc0, acc1;
#pragma unroll
  for (int r = 0; r < 16; ++r) { zacc[r] = 0.f; acc0[r] = 0.f; acc1[r] = 0.f; }
  float m0 = -1e30f, m1 = -1e30f, s0 = 0.f, s1 = 0.f;

  B8 ka0, ka1, va0, va1, kb0, kb1, vb0, vb1;
  ka0.u = *(const uint4v*)(kT);        ka1.u = *(const uint4v*)(kT + 16);
  va0.u = *(const uint4v*)(vT);        va1.u = *(const uint4v*)(vT + 16);
  kb0.u = *(const uint4v*)(kT + 1024); kb1.u = *(const uint4v*)(kT + 1024 + 16);
  vb0.u = *(const uint4v*)(vT + 1024); vb1.u = *(const uint4v*)(vT + 1024 + 16);

  for (int ti = 0; ti < 32; ti += 2) {
    const int off = ti << 10;
    TILE(ka0, ka1, va0, va1, off + 2048)   // last-iter over-read stays inside ws (next region)
    TILE(kb0, kb1, vb0, vb1, off + 3072)
  }

  if (wid) {
    const int w = wid - 1;
    sm_[w][0][lane] = m0; sm_[w][1][lane] = m1;
    ss_[w][0][lane] = s0; ss_[w][1][lane] = s1;
#pragma unroll
    for (int r = 0; r < 16; ++r) { sa_[w][0][r][lane] = acc0[r]; sa_[w][1][r][lane] = acc1[r]; }
  }
  __syncthreads();
  if (wid == 0) {
#pragma unroll
    for (int g = 0; g < 2; ++g) {
      float m = g ? m1 : m0, s = g ? s1 : s0;
      float mm = m;
#pragma unroll
      for (int w = 0; w < 3; ++w) mm = fmaxf(mm, sm_[w][g][lane]);
      float e = EX2(m - mm);
      float den = s * e;
      float ew[3];
#pragma unroll
      for (int w = 0; w < 3; ++w) {
        ew[w] = EX2(sm_[w][g][lane] - mm);
        den += ss_[w][g][lane] * ew[w];
      }
      float inv = 0.5f / den;
      u16* yp = yT + (size_t)bh * 32 * SQ + qbase + g * 32 + l31;
#pragma unroll
      for (int r = 0; r < 16; ++r) {
        float o = (g ? acc1[r] : acc0[r]) * e;
#pragma unroll
        for (int w = 0; w < 3; ++w) o += sa_[w][g][r][lane] * ew[w];
        int row = (r & 3) + 8 * (r >> 2) + 4 * hi;
        yp[(size_t)row * SQ] = f2bf(o * inv);
      }
    }
  }
}

// ---------------- K4: out[b,p,d] = sum_f WoT[f,d]*y[b,f,p] + c[b,d]
__global__ __launch_bounds__(256) void kout(const u16* __restrict__ yT,
                                            const float* __restrict__ woT,
                                            const float* __restrict__ cvec,
                                            float* __restrict__ out) {
  __shared__ float yS[DM][16];
  const int t = threadIdx.x;
  const int b = blockIdx.y;
  const int P0 = blockIdx.x * 16;
  for (int idx = t; idx < DM * 16; idx += 256) {
    int f = idx >> 4, p = idx & 15;
    yS[f][p] = bf2f(yT[((size_t)b * DM + f) * SQ + P0 + p]);
  }
  __syncthreads();
  const int d4 = (t & 31) * 4;
  const int pg = (t >> 5) * 2;
  f32x4 a0 = {0.f, 0.f, 0.f, 0.f}, a1 = {0.f, 0.f, 0.f, 0.f};
  for (int f = 0; f < DM; ++f) {
    f32x4 wv = *(const f32x4*)&woT[f * DM + d4];
    float y0 = yS[f][pg], y1 = yS[f][pg + 1];
    a0 += wv * y0;
    a1 += wv * y1;
  }
  f32x4 cv = *(const f32x4*)&cvec[b * DM + d4];
  a0 += cv; a1 += cv;
  *(f32x4*)&out[((size_t)b * SQ + P0 + pg) * DM + d4] = a0;
  *(f32x4*)&out[((size_t)b * SQ + P0 + pg + 1) * DM + d4] = a1;
}

extern "C" void kernel_launch(void* const* d_in, const int* in_sizes, int n_in,
                              void* d_out, int out_size, void* d_ws, size_t ws_size,
                              hipStream_t stream) {
  const float* x  = (const float*)d_in[0];
  const float* Wk = (const float*)d_in[1];
  const float* Wq = (const float*)d_in[2];
  const float* Wv = (const float*)d_in[3];
  const float* Wo = (const float*)d_in[4];
  float* out = (float*)d_out;
  char* ws = (char*)d_ws;
  // total footprint: 256KB aux + 6MB qkv + 2MB yT = 8.25MB (< 10MB proven in round 1)
  float* woT  = (float*)(ws);                        // 64 KB
  float* xsum = (float*)(ws + (64 << 10));           // 1 KB
  float* cvec = (float*)(ws + (68 << 10));           // 1 KB
  u16* qb = (u16*)(ws + (256 << 10));                // 2 MB
  u16* kb = (u16*)(ws + (256 << 10) + ((size_t)2 << 20));
  u16* vt = (u16*)(ws + (256 << 10) + ((size_t)4 << 20));
  u16* yT = (u16*)(ws + (256 << 10) + ((size_t)6 << 20));  // 2 MB bf16

  hipMemsetAsync(xsum, 0, NB * DM * sizeof(float), stream);
  kprep<<<dim3(33), dim3(256), 0, stream>>>(x, Wo, woT, xsum);
  kprojc<<<dim3(64, 13), dim3(256), 0, stream>>>(x, Wk, Wq, Wv, Wo, xsum, qb, kb, vt, cvec);
  kattn<<<dim3(64, 8), dim3(256), 0, stream>>>(qb, kb, vt, yT);
  kout<<<dim3(256, 2), dim3(256), 0, stream>>>(yT, woT, cvec, out);
}

// Round 4
// 141.716 us; speedup vs baseline: 1.5879x; 1.1295x over previous
//
#include <hip/hip_runtime.h>

#define SQ 4096
#define NB 2
#define NH 4
#define DH 32
#define DM 128

typedef float f32x16 __attribute__((ext_vector_type(16)));
typedef float f32x4  __attribute__((ext_vector_type(4)));
typedef __bf16 bf16x8 __attribute__((ext_vector_type(8)));
typedef unsigned int uint4v __attribute__((ext_vector_type(4)));
typedef unsigned short u16;

union B8 { uint4v u; bf16x8 b; };

__device__ inline u16 f2bf(float x) {
  unsigned u = __builtin_bit_cast(unsigned, x);
  unsigned r = (u + 0x7FFF + ((u >> 16) & 1)) >> 16;
  return (u16)r;
}

__device__ inline float bf2f(u16 v) {
  return __builtin_bit_cast(float, (unsigned)v << 16);
}

__device__ inline unsigned cvt_pk_bf16(float a, float b) {
  unsigned r;
  asm("v_cvt_pk_bf16_f32 %0, %1, %2" : "=v"(r) : "v"(a), "v"(b));
  return r;
}

__device__ inline void swap32(unsigned &a, unsigned &b) {
  asm("v_permlane32_swap_b32 %0, %1" : "+v"(a), "+v"(b));
}

#if __has_builtin(__builtin_amdgcn_exp2f)
#define EX2 __builtin_amdgcn_exp2f
#else
#define EX2 exp2f
#endif

__device__ inline float xhalf_max(float x) {
  unsigned ua = __builtin_bit_cast(unsigned, x), ub = ua;
  asm("v_permlane32_swap_b32 %0, %1" : "+v"(ua), "+v"(ub));
  return fmaxf(__builtin_bit_cast(float, ua), __builtin_bit_cast(float, ub));
}

__device__ inline float xhalf_add(float x) {
  unsigned ua = __builtin_bit_cast(unsigned, x), ub = ua;
  asm("v_permlane32_swap_b32 %0, %1" : "+v"(ua), "+v"(ub));
  return __builtin_bit_cast(float, ua) + __builtin_bit_cast(float, ub);
}

__device__ inline float tmax16(const f32x16& v) {
  float a0 = fmaxf(v[0], v[1]), a1 = fmaxf(v[2], v[3]);
  float a2 = fmaxf(v[4], v[5]), a3 = fmaxf(v[6], v[7]);
  float a4 = fmaxf(v[8], v[9]), a5 = fmaxf(v[10], v[11]);
  float a6 = fmaxf(v[12], v[13]), a7 = fmaxf(v[14], v[15]);
  float b0 = fmaxf(a0, a1), b1 = fmaxf(a2, a3);
  float b2 = fmaxf(a4, a5), b3 = fmaxf(a6, a7);
  return fmaxf(fmaxf(b0, b1), fmaxf(b2, b3));
}

// ---------------- K1: prep — xb bf16 (256 blk), xsum (128 blk), weights (4 blk)
__global__ __launch_bounds__(256) void kprep(const float* __restrict__ x,
                                             const float* __restrict__ Wk,
                                             const float* __restrict__ Wq,
                                             const float* __restrict__ Wv,
                                             const float* __restrict__ Wo,
                                             u16* __restrict__ xb,
                                             u16* __restrict__ wb,
                                             float* __restrict__ woT,
                                             float* __restrict__ xsum) {
  const int bid = blockIdx.x, t = threadIdx.x;
  if (bid < 256) {
    // x -> bf16, 16 elems/thread
    const size_t base = (size_t)bid * 4096 + (size_t)t * 16;
    const f32x4* src = (const f32x4*)(x + base);
    uint4v* dst = (uint4v*)(xb + base);
    f32x4 v0 = src[0], v1 = src[1], v2 = src[2], v3 = src[3];
    uint4v o0, o1;
    o0[0] = cvt_pk_bf16(v0[0], v0[1]); o0[1] = cvt_pk_bf16(v0[2], v0[3]);
    o0[2] = cvt_pk_bf16(v1[0], v1[1]); o0[3] = cvt_pk_bf16(v1[2], v1[3]);
    o1[0] = cvt_pk_bf16(v2[0], v2[1]); o1[1] = cvt_pk_bf16(v2[2], v2[3]);
    o1[2] = cvt_pk_bf16(v3[0], v3[1]); o1[3] = cvt_pk_bf16(v3[2], v3[3]);
    dst[0] = o0; dst[1] = o1;
  } else if (bid < 384) {
    // xsum: 128 blocks x 64 rows
    const int j = bid - 256;
    const int b = j >> 6, rblk = j & 63;
    const int d = t & 127, rh = t >> 7;
    const float* xp = x + ((size_t)b * SQ + rblk * 64) * DM + d;
    float a = 0.f;
    for (int r = rh; r < 64; r += 2) a += xp[(size_t)r * DM];
    __shared__ float red[2][DM];
    red[rh][d] = a;
    __syncthreads();
    if (t < DM) atomicAdd(&xsum[b * DM + t], red[0][t] + red[1][t]);
  } else {
    const int m = bid - 384;
    if (m < 3) {
      const float* W = (m == 0) ? Wk : (m == 1 ? Wq : Wv);
      const float s = (m == 1) ? (1.4426950408889634f / 5.656854249492380f) : 1.0f;
      for (int i = t; i < DM * DM; i += 256) wb[m * DM * DM + i] = f2bf(W[i] * s);
    } else {
      for (int i = t; i < DM * DM; i += 256) woT[(i & 127) * DM + (i >> 7)] = Wo[i];
    }
  }
}

// ---------------- K2: MFMA projections from bf16 xb/wb (+ fused cvec at by==12)
// qb/kb: bf16 [bh][p][dh]; vt: bf16 [bh][ptile][dh][p%32]
__global__ __launch_bounds__(256) void kprojc(const u16* __restrict__ xb,
                                              const u16* __restrict__ wb,
                                              const float* __restrict__ Wv,
                                              const float* __restrict__ Wo,
                                              const float* __restrict__ xsum,
                                              u16* __restrict__ qb,
                                              u16* __restrict__ kb,
                                              u16* __restrict__ vt,
                                              float* __restrict__ cvec) {
  const int by = blockIdx.y;
  const int t = threadIdx.x;
  if (by == 12) {
    // cvec: c[b][d] = 0.5 * Wo @ (Wv @ xsum)
    if (blockIdx.x >= NB) return;
    const int b = blockIdx.x;
    __shared__ float xs[DM], vs[DM];
    if (t < DM) xs[t] = xsum[b * DM + t];
    __syncthreads();
    const int c = t >> 1, half = t & 1;
    float a = 0.f;
    const float* wr = Wv + c * DM + half * 64;
    const float* xh = xs + half * 64;
    for (int i = 0; i < 64; ++i) a += wr[i] * xh[i];
    a += __shfl_xor(a, 1, 64);
    if (half == 0) vs[c] = a;
    __syncthreads();
    float a2 = 0.f;
    const float* wr2 = Wo + c * DM + half * 64;
    const float* vh = vs + half * 64;
    for (int i = 0; i < 64; ++i) a2 += wr2[i] * vh[i];
    a2 += __shfl_xor(a2, 1, 64);
    if (half == 0) cvec[b * DM + c] = 0.5f * a2;
    return;
  }
  const int lane = t & 63, wid = t >> 6;
  const int l31 = lane & 31, hi = lane >> 5;
  const int mat = by >> 2, h = by & 3;   // 0:K 1:Q(prescaled) 2:V
  const int p0 = (blockIdx.x * 4 + wid) * 32;
  const u16* xrow = xb + (size_t)(p0 + l31) * DM + 8 * hi;
  const u16* wrow = wb + mat * DM * DM + (h * 32 + l31) * DM + 8 * hi;
  f32x16 acc;
#pragma unroll
  for (int r = 0; r < 16; ++r) acc[r] = 0.f;
#pragma unroll
  for (int ks = 0; ks < 8; ++ks) {
    B8 a, w;
    a.u = *(const uint4v*)(xrow + ks * 16);
    w.u = *(const uint4v*)(wrow + ks * 16);
    acc = __builtin_amdgcn_mfma_f32_32x32x16_bf16(a.b, w.b, acc, 0, 0, 0);
  }
  const int b = p0 >> 12, pl = p0 & (SQ - 1);
  const size_t bh = (size_t)b * NH + h;
  if (mat < 2) {
    u16* dst = (mat ? qb : kb) + (bh * SQ + pl) * DH + l31;
#pragma unroll
    for (int r = 0; r < 16; ++r) {
      int row = (r & 3) + 8 * (r >> 2) + 4 * hi;
      dst[(size_t)row * DH] = f2bf(acc[r]);
    }
  } else {
    u16* dst = vt + ((bh * (SQ / 32) + (pl >> 5)) * DH + l31) * 32;
#pragma unroll
    for (int r = 0; r < 16; ++r) {
      int row = (r & 3) + 8 * (r >> 2) + 4 * hi;
      dst[row] = f2bf(acc[r]);
    }
  }
}

// ---------------- K3: fused attention, 64 q per wave, keys 4-way split per block
#define SOFTMAX_PV(SC, M, S, ACC, V0, V1) {                                    \
  float p_[16];                                                                \
  _Pragma("unroll") for (int r = 0; r < 16; ++r) p_[r] = EX2(SC[r] - M);       \
  float ls = ((p_[0]+p_[1])+(p_[2]+p_[3]))+((p_[4]+p_[5])+(p_[6]+p_[7]));      \
  ls += ((p_[8]+p_[9])+(p_[10]+p_[11]))+((p_[12]+p_[13])+(p_[14]+p_[15]));     \
  S += xhalf_add(ls);                                                          \
  unsigned w0 = cvt_pk_bf16(p_[0], p_[1]),  w1 = cvt_pk_bf16(p_[2], p_[3]);    \
  unsigned w2 = cvt_pk_bf16(p_[4], p_[5]),  w3 = cvt_pk_bf16(p_[6], p_[7]);    \
  unsigned w4 = cvt_pk_bf16(p_[8], p_[9]),  w5 = cvt_pk_bf16(p_[10], p_[11]);  \
  unsigned w6 = cvt_pk_bf16(p_[12], p_[13]), w7 = cvt_pk_bf16(p_[14], p_[15]); \
  swap32(w0, w2); swap32(w1, w3); swap32(w4, w6); swap32(w5, w7);              \
  B8 bp0_, bp1_;                                                               \
  bp0_.u[0] = w0; bp0_.u[1] = w1; bp0_.u[2] = w2; bp0_.u[3] = w3;              \
  bp1_.u[0] = w4; bp1_.u[1] = w5; bp1_.u[2] = w6; bp1_.u[3] = w7;              \
  ACC = __builtin_amdgcn_mfma_f32_32x32x16_bf16(V0.b, bp0_.b, ACC, 0, 0, 0);   \
  ACC = __builtin_amdgcn_mfma_f32_32x32x16_bf16(V1.b, bp1_.b, ACC, 0, 0, 0);   \
}

#define TILE(K0, K1, V0, V1, NOFF) {                                             \
  f32x16 sc0 = __builtin_amdgcn_mfma_f32_32x32x16_bf16(K0.b, qf00.b, zacc, 0,0,0); \
  sc0 = __builtin_amdgcn_mfma_f32_32x32x16_bf16(K1.b, qf01.b, sc0, 0, 0, 0);     \
  f32x16 sc1 = __builtin_amdgcn_mfma_f32_32x32x16_bf16(K0.b, qf10.b, zacc, 0,0,0); \
  sc1 = __builtin_amdgcn_mfma_f32_32x32x16_bf16(K1.b, qf11.b, sc1, 0, 0, 0);     \
  K0.u = *(const uint4v*)(kT + (NOFF));                                          \
  K1.u = *(const uint4v*)(kT + (NOFF) + 16);                                     \
  float pm0 = xhalf_max(tmax16(sc0));                                            \
  float pm1 = xhalf_max(tmax16(sc1));                                            \
  if (__any((pm0 > m0 + 8.f) | (pm1 > m1 + 8.f))) {                              \
    float n0 = fmaxf(m0, pm0), n1 = fmaxf(m1, pm1);                              \
    float r0 = EX2(m0 - n0), r1 = EX2(m1 - n1);                                  \
    s0 *= r0; s1 *= r1;                                                          \
    _Pragma("unroll") for (int r = 0; r < 16; ++r) { acc0[r] *= r0; acc1[r] *= r1; } \
    m0 = n0; m1 = n1;                                                            \
  }                                                                              \
  SOFTMAX_PV(sc0, m0, s0, acc0, V0, V1)                                          \
  SOFTMAX_PV(sc1, m1, s1, acc1, V0, V1)                                          \
  V0.u = *(const uint4v*)(vT + (NOFF));                                          \
  V1.u = *(const uint4v*)(vT + (NOFF) + 16);                                     \
}

__global__ __launch_bounds__(256) void kattn(const u16* __restrict__ qb,
                                             const u16* __restrict__ kb,
                                             const u16* __restrict__ vt,
                                             u16* __restrict__ yT) {
  __shared__ float sm_[3][2][64], ss_[3][2][64], sa_[3][2][16][64];
  const int t = threadIdx.x, lane = t & 63, wid = t >> 6;
  const int l31 = lane & 31, hi = lane >> 5;
  const int bh = blockIdx.y;
  const int qbase = blockIdx.x * 64;

  const u16* qrow0 = qb + ((size_t)bh * SQ + qbase + l31) * DH + 8 * hi;
  const u16* qrow1 = qrow0 + 32 * DH;
  B8 qf00, qf01, qf10, qf11;
  qf00.u = *(const uint4v*)(qrow0);
  qf01.u = *(const uint4v*)(qrow0 + 16);
  qf10.u = *(const uint4v*)(qrow1);
  qf11.u = *(const uint4v*)(qrow1 + 16);

  const int kh = wid;  // key quarter: 1024 keys per wave
  const u16* kT = kb + ((size_t)bh * SQ + kh * 1024) * DH + l31 * 32 + 8 * hi;
  const u16* vT = vt + ((size_t)bh * (SQ / 32) + kh * 32) * (DH * 32) + l31 * 32 + 8 * hi;

  f32x16 zacc, acc0, acc1;
#pragma unroll
  for (int r = 0; r < 16; ++r) { zacc[r] = 0.f; acc0[r] = 0.f; acc1[r] = 0.f; }
  float m0 = -1e30f, m1 = -1e30f, s0 = 0.f, s1 = 0.f;

  B8 ka0, ka1, va0, va1, kb0, kb1, vb0, vb1;
  ka0.u = *(const uint4v*)(kT);        ka1.u = *(const uint4v*)(kT + 16);
  va0.u = *(const uint4v*)(vT);        va1.u = *(const uint4v*)(vT + 16);
  kb0.u = *(const uint4v*)(kT + 1024); kb1.u = *(const uint4v*)(kT + 1024 + 16);
  vb0.u = *(const uint4v*)(vT + 1024); vb1.u = *(const uint4v*)(vT + 1024 + 16);

  for (int ti = 0; ti < 32; ti += 2) {
    const int off = ti << 10;
    TILE(ka0, ka1, va0, va1, off + 2048)   // last-iter over-read stays inside ws (next region)
    TILE(kb0, kb1, vb0, vb1, off + 3072)
  }

  if (wid) {
    const int w = wid - 1;
    sm_[w][0][lane] = m0; sm_[w][1][lane] = m1;
    ss_[w][0][lane] = s0; ss_[w][1][lane] = s1;
#pragma unroll
    for (int r = 0; r < 16; ++r) { sa_[w][0][r][lane] = acc0[r]; sa_[w][1][r][lane] = acc1[r]; }
  }
  __syncthreads();
  if (wid == 0) {
#pragma unroll
    for (int g = 0; g < 2; ++g) {
      float m = g ? m1 : m0, s = g ? s1 : s0;
      float mm = m;
#pragma unroll
      for (int w = 0; w < 3; ++w) mm = fmaxf(mm, sm_[w][g][lane]);
      float e = EX2(m - mm);
      float den = s * e;
      float ew[3];
#pragma unroll
      for (int w = 0; w < 3; ++w) {
        ew[w] = EX2(sm_[w][g][lane] - mm);
        den += ss_[w][g][lane] * ew[w];
      }
      float inv = 0.5f / den;
      u16* yp = yT + (size_t)bh * 32 * SQ + qbase + g * 32 + l31;
#pragma unroll
      for (int r = 0; r < 16; ++r) {
        float o = (g ? acc1[r] : acc0[r]) * e;
#pragma unroll
        for (int w = 0; w < 3; ++w) o += sa_[w][g][r][lane] * ew[w];
        int row = (r & 3) + 8 * (r >> 2) + 4 * hi;
        yp[(size_t)row * SQ] = f2bf(o * inv);
      }
    }
  }
}

// ---------------- K4: out[b,p,d] = sum_f WoT[f,d]*y[b,f,p] + c[b,d]
__global__ __launch_bounds__(256) void kout(const u16* __restrict__ yT,
                                            const float* __restrict__ woT,
                                            const float* __restrict__ cvec,
                                            float* __restrict__ out) {
  __shared__ float yS[DM][16];
  const int t = threadIdx.x;
  const int b = blockIdx.y;
  const int P0 = blockIdx.x * 16;
  for (int idx = t; idx < DM * 16; idx += 256) {
    int f = idx >> 4, p = idx & 15;
    yS[f][p] = bf2f(yT[((size_t)b * DM + f) * SQ + P0 + p]);
  }
  __syncthreads();
  const int d4 = (t & 31) * 4;
  const int pg = (t >> 5) * 2;
  f32x4 a0 = {0.f, 0.f, 0.f, 0.f}, a1 = {0.f, 0.f, 0.f, 0.f};
  for (int f = 0; f < DM; ++f) {
    f32x4 wv = *(const f32x4*)&woT[f * DM + d4];
    float y0 = yS[f][pg], y1 = yS[f][pg + 1];
    a0 += wv * y0;
    a1 += wv * y1;
  }
  f32x4 cv = *(const f32x4*)&cvec[b * DM + d4];
  a0 += cv; a1 += cv;
  *(f32x4*)&out[((size_t)b * SQ + P0 + pg) * DM + d4] = a0;
  *(f32x4*)&out[((size_t)b * SQ + P0 + pg + 1) * DM + d4] = a1;
}

extern "C" void kernel_launch(void* const* d_in, const int* in_sizes, int n_in,
                              void* d_out, int out_size, void* d_ws, size_t ws_size,
                              hipStream_t stream) {
  const float* x  = (const float*)d_in[0];
  const float* Wk = (const float*)d_in[1];
  const float* Wq = (const float*)d_in[2];
  const float* Wv = (const float*)d_in[3];
  const float* Wo = (const float*)d_in[4];
  float* out = (float*)d_out;
  char* ws = (char*)d_ws;
  // layout (8.25 MB total, proven-safe budget):
  //   aux 256 KB: woT @0 (64K), xsum @64K, cvec @68K, wb @80K (96K)
  //   qb @256K (2M), kb (2M), vt (2M), yT/xb aliased (2M bf16)
  float* woT  = (float*)(ws);
  float* xsum = (float*)(ws + (64 << 10));
  float* cvec = (float*)(ws + (68 << 10));
  u16* wb = (u16*)(ws + (80 << 10));
  u16* qb = (u16*)(ws + (256 << 10));
  u16* kb = (u16*)(ws + (256 << 10) + ((size_t)2 << 20));
  u16* vt = (u16*)(ws + (256 << 10) + ((size_t)4 << 20));
  u16* yT = (u16*)(ws + (256 << 10) + ((size_t)6 << 20));  // also xb (consumed before yT written)
  u16* xb = yT;

  hipMemsetAsync(xsum, 0, NB * DM * sizeof(float), stream);
  kprep<<<dim3(388), dim3(256), 0, stream>>>(x, Wk, Wq, Wv, Wo, xb, wb, woT, xsum);
  kprojc<<<dim3(64, 13), dim3(256), 0, stream>>>(xb, wb, Wv, Wo, xsum, qb, kb, vt, cvec);
  kattn<<<dim3(64, 8), dim3(256), 0, stream>>>(qb, kb, vt, yT);
  kout<<<dim3(256, 2), dim3(256), 0, stream>>>(yT, woT, cvec, out);
}

// Round 5
// 124.324 us; speedup vs baseline: 1.8101x; 1.1399x over previous
//
#include <hip/hip_runtime.h>

#define SQ 4096
#define NB 2
#define NH 4
#define DH 32
#define DM 128

typedef float f32x16 __attribute__((ext_vector_type(16)));
typedef float f32x4  __attribute__((ext_vector_type(4)));
typedef __bf16 bf16x8 __attribute__((ext_vector_type(8)));
typedef unsigned int uint4v __attribute__((ext_vector_type(4)));
typedef unsigned short u16;

union B8 { uint4v u; bf16x8 b; };

__device__ inline u16 f2bf(float x) {
  unsigned u = __builtin_bit_cast(unsigned, x);
  unsigned r = (u + 0x7FFF + ((u >> 16) & 1)) >> 16;
  return (u16)r;
}

__device__ inline unsigned cvt_pk_bf16(float a, float b) {
  unsigned r;
  asm("v_cvt_pk_bf16_f32 %0, %1, %2" : "=v"(r) : "v"(a), "v"(b));
  return r;
}

__device__ inline void swap32(unsigned &a, unsigned &b) {
  asm("v_permlane32_swap_b32 %0, %1" : "+v"(a), "+v"(b));
}

#if __has_builtin(__builtin_amdgcn_exp2f)
#define EX2 __builtin_amdgcn_exp2f
#else
#define EX2 exp2f
#endif

__device__ inline float xhalf_max(float x) {
  unsigned ua = __builtin_bit_cast(unsigned, x), ub = ua;
  asm("v_permlane32_swap_b32 %0, %1" : "+v"(ua), "+v"(ub));
  return fmaxf(__builtin_bit_cast(float, ua), __builtin_bit_cast(float, ub));
}

__device__ inline float xhalf_add(float x) {
  unsigned ua = __builtin_bit_cast(unsigned, x), ub = ua;
  asm("v_permlane32_swap_b32 %0, %1" : "+v"(ua), "+v"(ub));
  return __builtin_bit_cast(float, ua) + __builtin_bit_cast(float, ub);
}

// max of 16 via v_max3 fusion (nested fmax triples)
__device__ inline float tmax16(const f32x16& v) {
  float a0 = fmaxf(fmaxf(v[0], v[1]), v[2]);
  float a1 = fmaxf(fmaxf(v[3], v[4]), v[5]);
  float a2 = fmaxf(fmaxf(v[6], v[7]), v[8]);
  float a3 = fmaxf(fmaxf(v[9], v[10]), v[11]);
  float a4 = fmaxf(fmaxf(v[12], v[13]), v[14]);
  float b0 = fmaxf(fmaxf(a0, a1), a2);
  float b1 = fmaxf(fmaxf(a3, a4), v[15]);
  return fmaxf(b0, b1);
}

// ---------------- K1: prep — xb bf16 (256 blk), xsum (128 blk), weights bf16 (4 blk)
__global__ __launch_bounds__(256) void kprep(const float* __restrict__ x,
                                             const float* __restrict__ Wk,
                                             const float* __restrict__ Wq,
                                             const float* __restrict__ Wv,
                                             const float* __restrict__ Wo,
                                             u16* __restrict__ xb,
                                             u16* __restrict__ wb,
                                             float* __restrict__ xsum) {
  const int bid = blockIdx.x, t = threadIdx.x;
  if (bid < 256) {
    // x -> bf16, 16 elems/thread
    const size_t base = (size_t)bid * 4096 + (size_t)t * 16;
    const f32x4* src = (const f32x4*)(x + base);
    uint4v* dst = (uint4v*)(xb + base);
    f32x4 v0 = src[0], v1 = src[1], v2 = src[2], v3 = src[3];
    uint4v o0, o1;
    o0[0] = cvt_pk_bf16(v0[0], v0[1]); o0[1] = cvt_pk_bf16(v0[2], v0[3]);
    o0[2] = cvt_pk_bf16(v1[0], v1[1]); o0[3] = cvt_pk_bf16(v1[2], v1[3]);
    o1[0] = cvt_pk_bf16(v2[0], v2[1]); o1[1] = cvt_pk_bf16(v2[2], v2[3]);
    o1[2] = cvt_pk_bf16(v3[0], v3[1]); o1[3] = cvt_pk_bf16(v3[2], v3[3]);
    dst[0] = o0; dst[1] = o1;
  } else if (bid < 384) {
    // xsum: 128 blocks x 64 rows
    const int j = bid - 256;
    const int b = j >> 6, rblk = j & 63;
    const int d = t & 127, rh = t >> 7;
    const float* xp = x + ((size_t)b * SQ + rblk * 64) * DM + d;
    float a = 0.f;
    for (int r = rh; r < 64; r += 2) a += xp[(size_t)r * DM];
    __shared__ float red[2][DM];
    red[rh][d] = a;
    __syncthreads();
    if (t < DM) atomicAdd(&xsum[b * DM + t], red[0][t] + red[1][t]);
  } else {
    const int m = bid - 384;  // 0:K 1:Q(prescaled) 2:V 3:O
    if (m < 3) {
      const float* W = (m == 0) ? Wk : (m == 1 ? Wq : Wv);
      const float s = (m == 1) ? (1.4426950408889634f / 5.656854249492380f) : 1.0f;
      for (int i = t; i < DM * DM; i += 256) wb[m * DM * DM + i] = f2bf(W[i] * s);
    } else {
      for (int i = t; i < DM * DM; i += 256) wb[3 * DM * DM + i] = f2bf(Wo[i]);
    }
  }
}

// ---------------- K2: MFMA projections from bf16 xb/wb (+ fused cvec at by==12)
// qb/kb: bf16 [bh][p][dh]; vt: bf16 [bh][ptile][dh][p%32]
__global__ __launch_bounds__(256) void kprojc(const u16* __restrict__ xb,
                                              const u16* __restrict__ wb,
                                              const float* __restrict__ Wv,
                                              const float* __restrict__ Wo,
                                              const float* __restrict__ xsum,
                                              u16* __restrict__ qb,
                                              u16* __restrict__ kb,
                                              u16* __restrict__ vt,
                                              float* __restrict__ cvec) {
  const int by = blockIdx.y;
  const int t = threadIdx.x;
  if (by == 12) {
    // cvec: c[b][d] = 0.5 * Wo @ (Wv @ xsum)
    if (blockIdx.x >= NB) return;
    const int b = blockIdx.x;
    __shared__ float xs[DM], vs[DM];
    if (t < DM) xs[t] = xsum[b * DM + t];
    __syncthreads();
    const int c = t >> 1, half = t & 1;
    float a = 0.f;
    const float* wr = Wv + c * DM + half * 64;
    const float* xh = xs + half * 64;
    for (int i = 0; i < 64; ++i) a += wr[i] * xh[i];
    a += __shfl_xor(a, 1, 64);
    if (half == 0) vs[c] = a;
    __syncthreads();
    float a2 = 0.f;
    const float* wr2 = Wo + c * DM + half * 64;
    const float* vh = vs + half * 64;
    for (int i = 0; i < 64; ++i) a2 += wr2[i] * vh[i];
    a2 += __shfl_xor(a2, 1, 64);
    if (half == 0) cvec[b * DM + c] = 0.5f * a2;
    return;
  }
  const int lane = t & 63, wid = t >> 6;
  const int l31 = lane & 31, hi = lane >> 5;
  const int mat = by >> 2, h = by & 3;   // 0:K 1:Q(prescaled) 2:V
  const int p0 = (blockIdx.x * 4 + wid) * 32;
  const u16* xrow = xb + (size_t)(p0 + l31) * DM + 8 * hi;
  const u16* wrow = wb + mat * DM * DM + (h * 32 + l31) * DM + 8 * hi;
  f32x16 acc;
#pragma unroll
  for (int r = 0; r < 16; ++r) acc[r] = 0.f;
#pragma unroll
  for (int ks = 0; ks < 8; ++ks) {
    B8 a, w;
    a.u = *(const uint4v*)(xrow + ks * 16);
    w.u = *(const uint4v*)(wrow + ks * 16);
    acc = __builtin_amdgcn_mfma_f32_32x32x16_bf16(a.b, w.b, acc, 0, 0, 0);
  }
  const int b = p0 >> 12, pl = p0 & (SQ - 1);
  const size_t bh = (size_t)b * NH + h;
  if (mat < 2) {
    u16* dst = (mat ? qb : kb) + (bh * SQ + pl) * DH + l31;
#pragma unroll
    for (int r = 0; r < 16; ++r) {
      int row = (r & 3) + 8 * (r >> 2) + 4 * hi;
      dst[(size_t)row * DH] = f2bf(acc[r]);
    }
  } else {
    u16* dst = vt + ((bh * (SQ / 32) + (pl >> 5)) * DH + l31) * 32;
#pragma unroll
    for (int r = 0; r < 16; ++r) {
      int row = (r & 3) + 8 * (r >> 2) + 4 * hi;
      dst[row] = f2bf(acc[r]);
    }
  }
}

// ---------------- K3: fused attention, 32 q per wave, keys 4-way split, 1024 blocks
#define TILE(K0, K1, V0, V1, NOFF) {                                               \
  f32x16 sc = __builtin_amdgcn_mfma_f32_32x32x16_bf16(K0.b, qf0.b, zacc, 0, 0, 0); \
  sc = __builtin_amdgcn_mfma_f32_32x32x16_bf16(K1.b, qf1.b, sc, 0, 0, 0);          \
  K0.u = *(const uint4v*)(kT + (NOFF));                                            \
  K1.u = *(const uint4v*)(kT + (NOFF) + 16);                                       \
  float pm = xhalf_max(tmax16(sc));                                                \
  if (__any(pm > m + 8.f)) {                                                       \
    float n = fmaxf(m, pm);                                                        \
    float rs = EX2(m - n);                                                         \
    s *= rs;                                                                       \
    _Pragma("unroll") for (int r = 0; r < 16; ++r) acc[r] *= rs;                   \
    m = n;                                                                         \
  }                                                                                \
  float p_[16];                                                                    \
  _Pragma("unroll") for (int r = 0; r < 16; ++r) p_[r] = EX2(sc[r] - m);           \
  float ls = ((p_[0]+p_[1])+(p_[2]+p_[3]))+((p_[4]+p_[5])+(p_[6]+p_[7]));          \
  ls += ((p_[8]+p_[9])+(p_[10]+p_[11]))+((p_[12]+p_[13])+(p_[14]+p_[15]));         \
  s += xhalf_add(ls);                                                              \
  unsigned w0 = cvt_pk_bf16(p_[0], p_[1]),  w1 = cvt_pk_bf16(p_[2], p_[3]);        \
  unsigned w2 = cvt_pk_bf16(p_[4], p_[5]),  w3 = cvt_pk_bf16(p_[6], p_[7]);        \
  unsigned w4 = cvt_pk_bf16(p_[8], p_[9]),  w5 = cvt_pk_bf16(p_[10], p_[11]);      \
  unsigned w6 = cvt_pk_bf16(p_[12], p_[13]), w7 = cvt_pk_bf16(p_[14], p_[15]);     \
  swap32(w0, w2); swap32(w1, w3); swap32(w4, w6); swap32(w5, w7);                  \
  B8 bp0_, bp1_;                                                                   \
  bp0_.u[0] = w0; bp0_.u[1] = w1; bp0_.u[2] = w2; bp0_.u[3] = w3;                  \
  bp1_.u[0] = w4; bp1_.u[1] = w5; bp1_.u[2] = w6; bp1_.u[3] = w7;                  \
  acc = __builtin_amdgcn_mfma_f32_32x32x16_bf16(V0.b, bp0_.b, acc, 0, 0, 0);       \
  acc = __builtin_amdgcn_mfma_f32_32x32x16_bf16(V1.b, bp1_.b, acc, 0, 0, 0);       \
  V0.u = *(const uint4v*)(vT + (NOFF));                                            \
  V1.u = *(const uint4v*)(vT + (NOFF) + 16);                                       \
}

__global__ __launch_bounds__(256, 4) void kattn(const u16* __restrict__ qb,
                                                const u16* __restrict__ kb,
                                                const u16* __restrict__ vt,
                                                u16* __restrict__ yb) {
  __shared__ float sm_[3][64], ss_[3][64], sa_[3][16][64];
  const int t = threadIdx.x, lane = t & 63, wid = t >> 6;
  const int l31 = lane & 31, hi = lane >> 5;
  const int bh = blockIdx.y;
  const int qbase = blockIdx.x * 32;

  const u16* qrow = qb + ((size_t)bh * SQ + qbase + l31) * DH + 8 * hi;
  B8 qf0, qf1;
  qf0.u = *(const uint4v*)(qrow);
  qf1.u = *(const uint4v*)(qrow + 16);

  const int kh = wid;  // key quarter: 1024 keys per wave
  const u16* kT = kb + ((size_t)bh * SQ + kh * 1024) * DH + l31 * 32 + 8 * hi;
  const u16* vT = vt + ((size_t)bh * (SQ / 32) + kh * 32) * (DH * 32) + l31 * 32 + 8 * hi;

  f32x16 zacc, acc;
#pragma unroll
  for (int r = 0; r < 16; ++r) { zacc[r] = 0.f; acc[r] = 0.f; }
  float m = -1e30f, s = 0.f;

  B8 ka0, ka1, va0, va1, kb0, kb1, vb0, vb1;
  ka0.u = *(const uint4v*)(kT);        ka1.u = *(const uint4v*)(kT + 16);
  va0.u = *(const uint4v*)(vT);        va1.u = *(const uint4v*)(vT + 16);
  kb0.u = *(const uint4v*)(kT + 1024); kb1.u = *(const uint4v*)(kT + 1024 + 16);
  vb0.u = *(const uint4v*)(vT + 1024); vb1.u = *(const uint4v*)(vT + 1024 + 16);

  for (int ti = 0; ti < 32; ti += 2) {
    const int off = ti << 10;
    TILE(ka0, ka1, va0, va1, off + 2048)   // last-iter over-read stays inside ws (next region)
    TILE(kb0, kb1, vb0, vb1, off + 3072)
  }

  if (wid) {
    const int w = wid - 1;
    sm_[w][lane] = m;
    ss_[w][lane] = s;
#pragma unroll
    for (int r = 0; r < 16; ++r) sa_[w][r][lane] = acc[r];
  }
  __syncthreads();
  if (wid == 0) {
    float mm = m;
#pragma unroll
    for (int w = 0; w < 3; ++w) mm = fmaxf(mm, sm_[w][lane]);
    float e = EX2(m - mm);
    float den = s * e;
    float ew[3];
#pragma unroll
    for (int w = 0; w < 3; ++w) {
      ew[w] = EX2(sm_[w][lane] - mm);
      den += ss_[w][lane] * ew[w];
    }
    float inv = 0.5f / den;
    const int b = bh >> 2, h = bh & 3;
    u16* yp = yb + ((size_t)(b * SQ) + qbase + l31) * DM + h * 32;
#pragma unroll
    for (int r = 0; r < 16; ++r) {
      float o = acc[r] * e;
#pragma unroll
      for (int w = 0; w < 3; ++w) o += sa_[w][r][lane] * ew[w];
      int row = (r & 3) + 8 * (r >> 2) + 4 * hi;  // f offset within head
      yp[row] = f2bf(o * inv);
    }
  }
}

// ---------------- K4 (MFMA): out[b,p,d] = sum_f yb[b,p,f]*Wo[d,f] + cvec[b,d]
// A = yb rows p (k=f contiguous), B = wob rows d (k=f contiguous)
// D[p=crow(r,hi)][d=l31] -> coalesced 128B store segments
__global__ __launch_bounds__(256) void kout(const u16* __restrict__ yb,
                                            const u16* __restrict__ wob,
                                            const float* __restrict__ cvec,
                                            float* __restrict__ out) {
  const int t = threadIdx.x, lane = t & 63, wid = t >> 6;
  const int l31 = lane & 31, hi = lane >> 5;
  const int blk = blockIdx.x;          // 256 blocks: [b(1)][ptile(128)]
  const int b = blk >> 7;
  const int p0 = (blk & 127) * 32;
  const int d0 = wid * 32;             // each wave: one 32-col d-tile
  const u16* yrow = yb + ((size_t)(b * SQ) + p0 + l31) * DM + 8 * hi;
  const u16* wrow = wob + (size_t)(d0 + l31) * DM + 8 * hi;
  f32x16 acc;
#pragma unroll
  for (int r = 0; r < 16; ++r) acc[r] = 0.f;
#pragma unroll
  for (int ks = 0; ks < 8; ++ks) {
    B8 a, w;
    a.u = *(const uint4v*)(yrow + ks * 16);
    w.u = *(const uint4v*)(wrow + ks * 16);
    acc = __builtin_amdgcn_mfma_f32_32x32x16_bf16(a.b, w.b, acc, 0, 0, 0);
  }
  float cv = cvec[b * DM + d0 + l31];
  float* op = out + ((size_t)(b * SQ) + p0) * DM + d0 + l31;
#pragma unroll
  for (int r = 0; r < 16; ++r) {
    int row = (r & 3) + 8 * (r >> 2) + 4 * hi;  // p offset
    op[(size_t)row * DM] = acc[r] + cv;
  }
}

extern "C" void kernel_launch(void* const* d_in, const int* in_sizes, int n_in,
                              void* d_out, int out_size, void* d_ws, size_t ws_size,
                              hipStream_t stream) {
  const float* x  = (const float*)d_in[0];
  const float* Wk = (const float*)d_in[1];
  const float* Wq = (const float*)d_in[2];
  const float* Wv = (const float*)d_in[3];
  const float* Wo = (const float*)d_in[4];
  float* out = (float*)d_out;
  char* ws = (char*)d_ws;
  // layout (8.25 MB total, proven-safe):
  //   aux 256KB: xsum @0 (1K), cvec @4K (1K), wb @64K (128K: K,Q,V,O bf16)
  //   qb @256K (2M), kb (2M), vt (2M), yb/xb aliased (2M)
  float* xsum = (float*)(ws);
  float* cvec = (float*)(ws + (4 << 10));
  u16* wb = (u16*)(ws + (64 << 10));
  u16* qb = (u16*)(ws + (256 << 10));
  u16* kb = (u16*)(ws + (256 << 10) + ((size_t)2 << 20));
  u16* vt = (u16*)(ws + (256 << 10) + ((size_t)4 << 20));
  u16* yb = (u16*)(ws + (256 << 10) + ((size_t)6 << 20));  // also xb (consumed before yb written)
  u16* xb = yb;

  hipMemsetAsync(xsum, 0, NB * DM * sizeof(float), stream);
  kprep<<<dim3(388), dim3(256), 0, stream>>>(x, Wk, Wq, Wv, Wo, xb, wb, xsum);
  kprojc<<<dim3(64, 13), dim3(256), 0, stream>>>(xb, wb, Wv, Wo, xsum, qb, kb, vt, cvec);
  kattn<<<dim3(128, 8), dim3(256), 0, stream>>>(qb, kb, vt, yb);
  kout<<<dim3(256), dim3(256), 0, stream>>>(yb, wb + 3 * DM * DM, cvec, out);
}